// Round 9
// baseline (250.475 us; speedup 1.0000x reference)
//
#include <hip/hip_runtime.h>

// MS Deformable Attention 3D — R11b: identical to R11 (infra failure, not
// kernel). GEMM1 hoisted to k_qproj (M=64 tiles, 4x less wcat L2 traffic,
// bf16 C), wcat columns interleaved (3s+{x,y,logit}), k_attn = stage C ->
// fused softmax+records -> gather -> out-proj with 40KB LDS (4 blocks/CU).

#define EE   256
#define HH   8
#define LL   4
#define NQq  10000
#define BSB  2
#define LENV 13294
#define MQ   16
#define ROWS_V (BSB * LENV)   // 26588
#define NROWS (BSB * NQq)     // 20000

// workspace layout (bytes):
//   wcat @ 0          : 393,216    (front guard for v_ws underreads >= -6464B)
//   v_ws @ 393,216    : 13,613,056
//   wval @ 14,006,272 : 131,072    (back guard for v_ws overreads)
//   wout @ 14,137,344 : 131,072
//   gC   @ 14,268,416 : 30,720,000 (20000 x 768 bf16)   total 44,988,416
#define VWS_OFF 393216
#define GC_OFF  14268416

typedef unsigned short u16;
typedef unsigned int   u32;
typedef __attribute__((ext_vector_type(8))) short bf16x8;
typedef __attribute__((ext_vector_type(4))) float f32x4;

__device__ __forceinline__ u32 bf16_of(float f) {
  u32 u = __float_as_uint(f);
  return (u + 0x7FFFu + ((u >> 16) & 1u)) >> 16;   // RNE
}
__device__ __forceinline__ float blo(u32 u) { return __uint_as_float(u << 16); }
__device__ __forceinline__ float bhi(u32 u) { return __uint_as_float(u & 0xFFFF0000u); }
__device__ __forceinline__ float b2f(u32 u) { return __uint_as_float(u << 16); }

__device__ __forceinline__ uint4 pack8(const float* f) {
  uint4 u;
  u.x = bf16_of(f[0]) | (bf16_of(f[1]) << 16);
  u.y = bf16_of(f[2]) | (bf16_of(f[3]) << 16);
  u.z = bf16_of(f[4]) | (bf16_of(f[5]) << 16);
  u.w = bf16_of(f[6]) | (bf16_of(f[7]) << 16);
  return u;
}

__device__ __forceinline__ void acc8(float o[8], uint4 q, float w) {
  o[0] += w * blo(q.x); o[1] += w * bhi(q.x);
  o[2] += w * blo(q.y); o[3] += w * bhi(q.y);
  o[4] += w * blo(q.z); o[5] += w * bhi(q.z);
  o[6] += w * blo(q.w); o[7] += w * bhi(q.w);
}

// ---- K0: weights -> bf16 B-fragment layout ----------------------------------
// wcat columns are INTERLEAVED: col = 3s+k, k=0 -> W_off[:,2s], k=1 ->
// W_off[:,2s+1], k=2 -> W_attn[:,s]. So C rows carry (ax,ay,logit) triples.
__global__ __launch_bounds__(64) void k_prep(
    const float* __restrict__ W_off, const float* __restrict__ W_attn,
    const float* __restrict__ W_val, const float* __restrict__ W_out,
    u16* __restrict__ wcat, u16* __restrict__ wval, u16* __restrict__ wout) {
  const int tile = blockIdx.x >> 3, s = blockIdx.x & 7;
  const int l = threadIdx.x, quad = l >> 4, r16 = l & 15;
  float f[8];
  u16* dst;
  if (tile < 48) {            // interleaved concat, 768 cols
    int col = tile * 16 + r16;
    int sc = col / 3, kp = col - sc * 3;
#pragma unroll
    for (int j = 0; j < 8; ++j) {
      int kk = s * 32 + quad * 8 + j;
      f[j] = (kp < 2) ? W_off[kk * 512 + 2 * sc + kp] : W_attn[kk * 256 + sc];
    }
    dst = wcat + ((tile * 8 + s) * 64 + l) * 8;
  } else if (tile < 64) {     // W_val[256x256]
    int col = (tile - 48) * 16 + r16;
#pragma unroll
    for (int j = 0; j < 8; ++j) f[j] = W_val[(s * 32 + quad * 8 + j) * 256 + col];
    dst = wval + (((tile - 48) * 8 + s) * 64 + l) * 8;
  } else {                    // W_out[256x256]
    int col = (tile - 64) * 16 + r16;
#pragma unroll
    for (int j = 0; j < 8; ++j) f[j] = W_out[(s * 32 + quad * 8 + j) * 256 + col];
    dst = wout + (((tile - 64) * 8 + s) * 64 + l) * 8;
  }
  *(uint4*)dst = pack8(f);
}

// ---- K1: value projection, MFMA, 64 rows/block, 512 threads / 8 waves -------
__global__ __launch_bounds__(512) void k_valproj(
    const float* __restrict__ value, const float* __restrict__ b_val,
    const u16* __restrict__ wval, u16* __restrict__ v_ws) {
  __shared__ __align__(16) u16 sA[64][264];
  const int tid = threadIdx.x;
  const int g0 = blockIdx.x * 64;
#pragma unroll
  for (int ch = 0; ch < 4; ++ch) {
    int fidx = ch * 4096 + tid * 8;
    int row = fidx >> 8, col = fidx & 255;
    int g = g0 + row;
    float fv[8] = {0.f, 0.f, 0.f, 0.f, 0.f, 0.f, 0.f, 0.f};
    if (g < ROWS_V) {
      float4 a = *(const float4*)(value + (long)g * 256 + col);
      float4 b = *(const float4*)(value + (long)g * 256 + col + 4);
      fv[0] = a.x; fv[1] = a.y; fv[2] = a.z; fv[3] = a.w;
      fv[4] = b.x; fv[5] = b.y; fv[6] = b.z; fv[7] = b.w;
    }
    *(uint4*)&sA[row][col] = pack8(fv);
  }
  __syncthreads();
  const int wave = tid >> 6, lane = tid & 63, quad = lane >> 4, r16 = lane & 15;
  f32x4 acc[2][4] = {};
  for (int s = 0; s < 8; ++s) {
    bf16x8 af[4];
#pragma unroll
    for (int mt = 0; mt < 4; ++mt)
      af[mt] = *(const bf16x8*)&sA[mt * 16 + r16][s * 32 + quad * 8];
#pragma unroll
    for (int nt = 0; nt < 2; ++nt) {
      int ntg = wave * 2 + nt;
      bf16x8 bfg = *(const bf16x8*)(wval + ((ntg * 8 + s) * 64 + lane) * 8);
#pragma unroll
      for (int mt = 0; mt < 4; ++mt)
        acc[nt][mt] = __builtin_amdgcn_mfma_f32_16x16x32_bf16(af[mt], bfg, acc[nt][mt], 0, 0, 0);
    }
  }
  __syncthreads();
#pragma unroll
  for (int nt = 0; nt < 2; ++nt) {
    int col = (wave * 2 + nt) * 16 + r16;
    float bias = b_val[col];
#pragma unroll
    for (int mt = 0; mt < 4; ++mt)
#pragma unroll
      for (int rr = 0; rr < 4; ++rr)
        sA[mt * 16 + quad * 4 + rr][col] = (u16)bf16_of(acc[nt][mt][rr] + bias);
  }
  __syncthreads();
#pragma unroll
  for (int it = 0; it < 4; ++it) {
    int chunk = it * 512 + tid;        // 0..2047
    int r  = chunk >> 5;               // row 0..63
    int hc = chunk & 31;               // head*4 + quarter
    int h2 = hc >> 2, qq = hc & 3;
    int g = g0 + r;
    if (g < ROWS_V) {
      int bb = g / LENV, pix = g - bb * LENV;
      *(uint4*)(v_ws + ((long)((bb * 8 + h2) * LENV + pix) * 32 + qq * 8)) =
          *(const uint4*)&sA[r][h2 * 32 + qq * 8];
    }
  }
}

// ---- K1b: C[20000][768] = (q+qpos) @ wcat, M=64 tiles, bf16 out -------------
__global__ __launch_bounds__(512) void k_qproj(
    const float* __restrict__ query, const float* __restrict__ query_pos,
    const u16* __restrict__ wcat, u16* __restrict__ gC) {
  __shared__ __align__(16) u16 sA[64][264];
  const int tid = threadIdx.x;
  const int g0 = blockIdx.x * 64;
#pragma unroll
  for (int ch = 0; ch < 4; ++ch) {
    int fidx = ch * 4096 + tid * 8;
    int row = fidx >> 8, col = fidx & 255;
    int g = g0 + row;
    float fv[8] = {0.f, 0.f, 0.f, 0.f, 0.f, 0.f, 0.f, 0.f};
    if (g < NROWS) {
      long base = (long)g * 256 + col;
      float4 a0 = *(const float4*)(query + base);
      float4 a1 = *(const float4*)(query + base + 4);
      float4 p0 = *(const float4*)(query_pos + base);
      float4 p1 = *(const float4*)(query_pos + base + 4);
      fv[0] = a0.x + p0.x; fv[1] = a0.y + p0.y; fv[2] = a0.z + p0.z; fv[3] = a0.w + p0.w;
      fv[4] = a1.x + p1.x; fv[5] = a1.y + p1.y; fv[6] = a1.z + p1.z; fv[7] = a1.w + p1.w;
    }
    *(uint4*)&sA[row][col] = pack8(fv);
  }
  __syncthreads();
  const int wave = tid >> 6, lane = tid & 63, quad = lane >> 4, r16 = lane & 15;
  f32x4 acc[6][4] = {};   // [n-tile][m-tile]
  for (int s = 0; s < 8; ++s) {
    bf16x8 af[4];
#pragma unroll
    for (int mt = 0; mt < 4; ++mt)
      af[mt] = *(const bf16x8*)&sA[mt * 16 + r16][s * 32 + quad * 8];
#pragma unroll
    for (int t6 = 0; t6 < 6; ++t6) {
      int tile = wave * 6 + t6;
      bf16x8 bfg = *(const bf16x8*)(wcat + ((tile * 8 + s) * 64 + lane) * 8);
#pragma unroll
      for (int mt = 0; mt < 4; ++mt)
        acc[t6][mt] = __builtin_amdgcn_mfma_f32_16x16x32_bf16(af[mt], bfg, acc[t6][mt], 0, 0, 0);
    }
  }
#pragma unroll
  for (int t6 = 0; t6 < 6; ++t6) {
    int col = (wave * 6 + t6) * 16 + r16;
#pragma unroll
    for (int mt = 0; mt < 4; ++mt)
#pragma unroll
      for (int rr = 0; rr < 4; ++rr) {
        int g = g0 + mt * 16 + quad * 4 + rr;
        if (g < NROWS) gC[(long)g * 768 + col] = (u16)bf16_of(acc[t6][mt][rr]);
      }
  }
}

// ---- K2: 16 queries/block, 512 threads; 40,960B LDS -> 4 blocks/CU ----------
__global__ __launch_bounds__(512, 8) void k_attn(
    const float* __restrict__ refpts,
    const float* __restrict__ b_off, const float* __restrict__ b_attn,
    const float* __restrict__ b_out,
    const u16* __restrict__ gC, const u16* __restrict__ wout,
    const char* __restrict__ wsb, float* __restrict__ out) {
  __shared__ __align__(16) char smem[40960];
  u16*  sG           = (u16*)smem;                  // staged C rows [16*768] (24,576B)
  uint2 (*sWgt)[256] = (uint2(*)[256])smem;         // 32KB, aliases sG (after barrier)
  u16   (*sOff)[256] = (u16(*)[256])(smem + 32768); // 8KB, disjoint from sG
  u16   (*sO)[264]   = (u16(*)[264])smem;           // gather out, aliases tables

  const int tid = threadIdx.x;
  const int g0 = blockIdx.x * MQ;
  const int b = g0 / NQq;
  const int wave = tid >> 6, lane = tid & 63, quad = lane >> 4, r16 = lane & 15;

  // phase 0: stage C rows (16 x 768 bf16, coalesced: 32 threads/row x 48B)
  {
    int row = tid >> 5, col = (tid & 31) * 24;
    const u16* src = gC + (long)(g0 + row) * 768 + col;
    u16* dst = sG + row * 768 + col;
    *(uint4*)(dst)      = *(const uint4*)(src);
    *(uint4*)(dst + 8)  = *(const uint4*)(src + 8);
    *(uint4*)(dst + 16) = *(const uint4*)(src + 16);
  }
  __syncthreads();

  // phase 1: fused softmax (32-lane shuffle) + record build.
  // thread = (s: 0..255, mh: 0..1); the 32 logits of (m,h) sit in 32
  // consecutive 32-aligned lanes. sOff (disjoint region) written directly;
  // sWgt buffered in regs (its region aliases sG).
  //   sOff = (o00/64 + 128) bits 0..13 | dy_flag bit 14
  uint2 wrecs[8];
  {
    const int s = tid & 255, mh = tid >> 8;
    const int l = (s >> 3) & 3;
    const int WlI[4] = {100, 50, 25, 13};
    const int baseI[4] = {0, 10000, 12500, 13125};
    const int Wl = WlI[l], Hl = WlI[l], base = baseI[l];
    const float WlF = (float)Wl;
    const float ba  = b_attn[s];
    const float box = b_off[2 * s], boy = b_off[2 * s + 1];
    const int jsw = (s & 224) | ((s + (s >> 5)) & 31);   // bank swizzle over h
#pragma unroll
    for (int mm = 0; mm < 8; ++mm) {
      int m = mh * 8 + mm;
      const u16* cp = sG + m * 768 + 3 * s;
      float ax = b2f(cp[0]), ay = b2f(cp[1]);
      float logit = b2f(cp[2]) + ba;
      float mx = logit;
      mx = fmaxf(mx, __shfl_xor(mx, 1));
      mx = fmaxf(mx, __shfl_xor(mx, 2));
      mx = fmaxf(mx, __shfl_xor(mx, 4));
      mx = fmaxf(mx, __shfl_xor(mx, 8));
      mx = fmaxf(mx, __shfl_xor(mx, 16));
      float e = __expf(logit - mx);
      float sum = e;
      sum += __shfl_xor(sum, 1);
      sum += __shfl_xor(sum, 2);
      sum += __shfl_xor(sum, 4);
      sum += __shfl_xor(sum, 8);
      sum += __shfl_xor(sum, 16);
      float w = e / sum;
      float2 rp = *(const float2*)(refpts + (((long)(g0 + m)) * LL + l) * 2);
      float x = rp.x * WlF + (ax + box) - 0.5f;
      float y = rp.y * WlF + (ay + boy) - 0.5f;
      float fx0 = floorf(x), fy0 = floorf(y);
      int x0 = (int)fx0, y0 = (int)fy0;
      float fx = x - fx0, fy = y - fy0;
      bool xv0 = (x0 >= 0) & (x0 < Wl);
      bool xv1 = (x0 >= -1) & (x0 < Wl - 1);
      bool yv0 = (y0 >= 0) & (y0 < Hl);
      bool yv1 = (y0 >= -1) & (y0 < Hl - 1);
      float w00 = w * (1.f - fx) * (1.f - fy) * (float)(xv0 & yv0);
      float w01 = w * fx * (1.f - fy) * (float)(xv1 & yv0);
      float w10 = w * (1.f - fx) * fy * (float)(xv0 & yv1);
      float w11 = w * fx * fy * (float)(xv1 & yv1);
      int x0a = min(max(x0, -1), Wl - 1);
      int y0a = min(max(y0, -1), Hl - 1);
      int y1c = min(max(y0 + 1, 0), Hl - 1);
      int o00u = base + y0a * Wl + x0a;              // 64B units, [-101, 13293]
      int dyf  = y1c - y0a;                          // 0 or 1
      wrecs[mm].x = bf16_of(w00) | (bf16_of(w01) << 16);
      wrecs[mm].y = bf16_of(w10) | (bf16_of(w11) << 16);
      sOff[m][jsw] = (u16)((o00u + 128) | (dyf << 14));
    }
  }
  __syncthreads();                       // sG dead
  {
    const int s = tid & 255, mh = tid >> 8;
    const int jsw = (s & 224) | ((s + (s >> 5)) & 31);
#pragma unroll
    for (int mm = 0; mm < 8; ++mm) sWgt[mh * 8 + mm][jsw] = wrecs[mm];
  }
  __syncthreads();

  // phase 2: gather — thread = (m:16, h:8, c4:4); level loop makes the dy
  // stride (Wl*64) a compile-time constant per 8-iteration group.
  {
    const int c4 = tid & 3, hh = (tid >> 2) & 7, m = tid >> 5;
    const u32 vbm = (u32)VWS_OFF + (u32)(b * 8 + hh) * (u32)(LENV * 64)
                  + (u32)c4 * 16u - 8192u;           // folds the +128 bias
    float oacc[8] = {};
    const u32 wl64tab[4] = {6400u, 3200u, 1600u, 832u};
#pragma unroll
    for (int lv = 0; lv < 4; ++lv) {
      const u32 wl64 = wl64tab[lv];
#pragma unroll 4
      for (int ii = 0; ii < 8; ++ii) {
        const int i = lv * 8 + ii;
        const int srow = (hh << 5) | ((i + hh) & 31);
        uint2 wr = sWgt[m][srow];
        u32   po = (u32)sOff[m][srow];
        u32 off0 = vbm + ((po & 0x3FFFu) << 6);
        u32 off1 = off0 + (po >> 14) * wl64;
        uint4 q00 = *(const uint4*)(wsb + off0);
        uint4 q01 = *(const uint4*)(wsb + off0 + 64);
        uint4 q10 = *(const uint4*)(wsb + off1);
        uint4 q11 = *(const uint4*)(wsb + off1 + 64);
        acc8(oacc, q00, blo(wr.x));
        acc8(oacc, q01, bhi(wr.x));
        acc8(oacc, q10, blo(wr.y));
        acc8(oacc, q11, bhi(wr.y));
      }
    }
    __syncthreads();                     // tables dead
    *(uint4*)&sO[m][hh * 32 + c4 * 8] = pack8(oacc);
  }
  __syncthreads();

  // phase 3: out = gathered @ W_out + b_out  (16 n-tiles / 8 waves)
  f32x4 acc2[2] = {};
  for (int s = 0; s < 8; ++s) {
    bf16x8 af = *(const bf16x8*)&sO[r16][s * 32 + quad * 8];
#pragma unroll
    for (int t2 = 0; t2 < 2; ++t2) {
      int tile = wave * 2 + t2;
      bf16x8 bfg = *(const bf16x8*)(wout + ((tile * 8 + s) * 64 + lane) * 8);
      acc2[t2] = __builtin_amdgcn_mfma_f32_16x16x32_bf16(af, bfg, acc2[t2], 0, 0, 0);
    }
  }
#pragma unroll
  for (int t2 = 0; t2 < 2; ++t2) {
    int col = (wave * 2 + t2) * 16 + r16;
    float bias = b_out[col];
#pragma unroll
    for (int rr = 0; rr < 4; ++rr) {
      int row = quad * 4 + rr;
      out[((long)(g0 + row)) * 256 + col] = acc2[t2][rr] + bias;
    }
  }
}

extern "C" void kernel_launch(void* const* d_in, const int* in_sizes, int n_in,
                              void* d_out, int out_size, void* d_ws, size_t ws_size,
                              hipStream_t stream) {
  const float* query     = (const float*)d_in[0];
  const float* value     = (const float*)d_in[1];
  const float* query_pos = (const float*)d_in[2];
  const float* refpts    = (const float*)d_in[3];
  const float* W_off     = (const float*)d_in[5];
  const float* b_off     = (const float*)d_in[6];
  const float* W_attn    = (const float*)d_in[7];
  const float* b_attn    = (const float*)d_in[8];
  const float* W_val     = (const float*)d_in[9];
  const float* b_val     = (const float*)d_in[10];
  const float* W_out     = (const float*)d_in[11];
  const float* b_out     = (const float*)d_in[12];
  float* out = (float*)d_out;

  char* ws = (char*)d_ws;
  u16* wcat = (u16*)ws;                                   //    393,216 B @ 0
  u16* v_ws = (u16*)(ws + VWS_OFF);                       // 13,613,056 B
  u16* wval = (u16*)(ws + VWS_OFF + 13613056);            //    131,072 B
  u16* wout = (u16*)(ws + VWS_OFF + 13613056 + 131072);   //    131,072 B
  u16* gC   = (u16*)(ws + GC_OFF);                        // 30,720,000 B

  k_prep<<<dim3(80 * 8), dim3(64), 0, stream>>>(W_off, W_attn, W_val, W_out,
                                                wcat, wval, wout);
  k_qproj<<<dim3((NROWS + 63) / 64), dim3(512), 0, stream>>>(query, query_pos, wcat, gC);
  k_valproj<<<dim3((ROWS_V + 63) / 64), dim3(512), 0, stream>>>(value, b_val, wval, v_ws);
  k_attn<<<dim3(BSB * NQq / MQ), dim3(512), 0, stream>>>(
      refpts, b_off, b_attn, b_out, gC, wout, ws, out);
}

// Round 10
// 236.086 us; speedup vs baseline: 1.0609x; 1.0609x over previous
//
#include <hip/hip_runtime.h>

// MS Deformable Attention 3D — R12: fused k_attn with bf16 sC (LDS 40,960B ->
// 4 blocks/CU, (512,8)), interleaved wcat triples; v_ws relaid as [b][pix][256]
// so k_valproj's epilogue is fully contiguous (gather offsets scale by 512B).

#define EE   256
#define HH   8
#define LL   4
#define NQq  10000
#define BSB  2
#define LENV 13294
#define MQ   16
#define ROWS_V (BSB * LENV)   // 26588

// workspace layout (bytes):
//   wcat @ 0          : 393,216    (front guard for v_ws underreads >= -52KB)
//   v_ws @ 393,216    : 13,613,056 ([b][pix][256] bf16, 512B rows)
//   wval @ 14,006,272 : 131,072    (back guard for v_ws overreads <= ~1KB)
//   wout @ 14,137,344 : 131,072
#define VWS_OFF 393216

typedef unsigned short u16;
typedef unsigned int   u32;
typedef __attribute__((ext_vector_type(8))) short bf16x8;
typedef __attribute__((ext_vector_type(4))) float f32x4;

__device__ __forceinline__ u32 bf16_of(float f) {
  u32 u = __float_as_uint(f);
  return (u + 0x7FFFu + ((u >> 16) & 1u)) >> 16;   // RNE
}
__device__ __forceinline__ float blo(u32 u) { return __uint_as_float(u << 16); }
__device__ __forceinline__ float bhi(u32 u) { return __uint_as_float(u & 0xFFFF0000u); }
__device__ __forceinline__ float b2f(u32 u) { return __uint_as_float(u << 16); }

__device__ __forceinline__ uint4 pack8(const float* f) {
  uint4 u;
  u.x = bf16_of(f[0]) | (bf16_of(f[1]) << 16);
  u.y = bf16_of(f[2]) | (bf16_of(f[3]) << 16);
  u.z = bf16_of(f[4]) | (bf16_of(f[5]) << 16);
  u.w = bf16_of(f[6]) | (bf16_of(f[7]) << 16);
  return u;
}

__device__ __forceinline__ void acc8(float o[8], uint4 q, float w) {
  o[0] += w * blo(q.x); o[1] += w * bhi(q.x);
  o[2] += w * blo(q.y); o[3] += w * bhi(q.y);
  o[4] += w * blo(q.z); o[5] += w * bhi(q.z);
  o[6] += w * blo(q.w); o[7] += w * bhi(q.w);
}

// ---- K0: weights -> bf16 B-fragment layout ----------------------------------
// wcat columns INTERLEAVED: col = 3s+k, k=0/1 -> W_off[:,2s+k], k=2 -> W_attn[:,s]
__global__ __launch_bounds__(64) void k_prep(
    const float* __restrict__ W_off, const float* __restrict__ W_attn,
    const float* __restrict__ W_val, const float* __restrict__ W_out,
    u16* __restrict__ wcat, u16* __restrict__ wval, u16* __restrict__ wout) {
  const int tile = blockIdx.x >> 3, s = blockIdx.x & 7;
  const int l = threadIdx.x, quad = l >> 4, r16 = l & 15;
  float f[8];
  u16* dst;
  if (tile < 48) {            // interleaved concat, 768 cols
    int col = tile * 16 + r16;
    int sc = col / 3, kp = col - sc * 3;
#pragma unroll
    for (int j = 0; j < 8; ++j) {
      int kk = s * 32 + quad * 8 + j;
      f[j] = (kp < 2) ? W_off[kk * 512 + 2 * sc + kp] : W_attn[kk * 256 + sc];
    }
    dst = wcat + ((tile * 8 + s) * 64 + l) * 8;
  } else if (tile < 64) {     // W_val[256x256]
    int col = (tile - 48) * 16 + r16;
#pragma unroll
    for (int j = 0; j < 8; ++j) f[j] = W_val[(s * 32 + quad * 8 + j) * 256 + col];
    dst = wval + (((tile - 48) * 8 + s) * 64 + l) * 8;
  } else {                    // W_out[256x256]
    int col = (tile - 64) * 16 + r16;
#pragma unroll
    for (int j = 0; j < 8; ++j) f[j] = W_out[(s * 32 + quad * 8 + j) * 256 + col];
    dst = wout + (((tile - 64) * 8 + s) * 64 + l) * 8;
  }
  *(uint4*)dst = pack8(f);
}

// ---- K1: value projection; v_ws rows are plain [g][256] bf16 (contiguous) ---
__global__ __launch_bounds__(512) void k_valproj(
    const float* __restrict__ value, const float* __restrict__ b_val,
    const u16* __restrict__ wval, u16* __restrict__ v_ws) {
  __shared__ __align__(16) u16 sA[64][264];
  const int tid = threadIdx.x;
  const int g0 = blockIdx.x * 64;
#pragma unroll
  for (int ch = 0; ch < 4; ++ch) {
    int fidx = ch * 4096 + tid * 8;
    int row = fidx >> 8, col = fidx & 255;
    int g = g0 + row;
    float fv[8] = {0.f, 0.f, 0.f, 0.f, 0.f, 0.f, 0.f, 0.f};
    if (g < ROWS_V) {
      float4 a = *(const float4*)(value + (long)g * 256 + col);
      float4 b = *(const float4*)(value + (long)g * 256 + col + 4);
      fv[0] = a.x; fv[1] = a.y; fv[2] = a.z; fv[3] = a.w;
      fv[4] = b.x; fv[5] = b.y; fv[6] = b.z; fv[7] = b.w;
    }
    *(uint4*)&sA[row][col] = pack8(fv);
  }
  __syncthreads();
  const int wave = tid >> 6, lane = tid & 63, quad = lane >> 4, r16 = lane & 15;
  f32x4 acc[2][4] = {};
  for (int s = 0; s < 8; ++s) {
    bf16x8 af[4];
#pragma unroll
    for (int mt = 0; mt < 4; ++mt)
      af[mt] = *(const bf16x8*)&sA[mt * 16 + r16][s * 32 + quad * 8];
#pragma unroll
    for (int nt = 0; nt < 2; ++nt) {
      int ntg = wave * 2 + nt;
      bf16x8 bfg = *(const bf16x8*)(wval + ((ntg * 8 + s) * 64 + lane) * 8);
#pragma unroll
      for (int mt = 0; mt < 4; ++mt)
        acc[nt][mt] = __builtin_amdgcn_mfma_f32_16x16x32_bf16(af[mt], bfg, acc[nt][mt], 0, 0, 0);
    }
  }
  __syncthreads();
#pragma unroll
  for (int nt = 0; nt < 2; ++nt) {
    int col = (wave * 2 + nt) * 16 + r16;
    float bias = b_val[col];
#pragma unroll
    for (int mt = 0; mt < 4; ++mt)
#pragma unroll
      for (int rr = 0; rr < 4; ++rr)
        sA[mt * 16 + quad * 4 + rr][col] = (u16)bf16_of(acc[nt][mt][rr] + bias);
  }
  __syncthreads();
  // contiguous epilogue: 64 rows x 512B = 32KB, 16B/thread/iter, coalesced
#pragma unroll
  for (int it = 0; it < 4; ++it) {
    int chunk = it * 512 + tid;        // 0..2047
    int r  = chunk >> 5;
    int cc = (chunk & 31) * 8;
    int g = g0 + r;
    if (g < ROWS_V)
      *(uint4*)(v_ws + (long)g * 256 + cc) = *(const uint4*)&sA[r][cc];
  }
}

// ---- K2: fused; 16 queries/block, 512 threads, 40,960B LDS -> 4 blocks/CU ---
__global__ __launch_bounds__(512, 8) void k_attn(
    const float* __restrict__ query, const float* __restrict__ query_pos,
    const float* __restrict__ refpts,
    const float* __restrict__ b_off, const float* __restrict__ b_attn,
    const float* __restrict__ b_out,
    const u16* __restrict__ wcat, const u16* __restrict__ wout,
    const char* __restrict__ wsb, float* __restrict__ out) {
  __shared__ __align__(16) char smem[40960];
  u16   (*sQ)[264]   = (u16(*)[264])smem;           // staged q (8,448B)
  u16   (*sC)[772]   = (u16(*)[772])smem;           // GEMM1 C bf16 (24,704B, after sQ)
  uint2 (*sWgt)[256] = (uint2(*)[256])smem;         // 32KB (after sC dead)
  u16   (*sOff)[256] = (u16(*)[256])(smem + 32768); // 8KB, disjoint from sC
  u16   (*sO)[264]   = (u16(*)[264])smem;           // gather out (after tables)

  const int tid = threadIdx.x;
  const int g0 = blockIdx.x * MQ;
  const int b = g0 / NQq;
  const int wave = tid >> 6, lane = tid & 63, quad = lane >> 4, r16 = lane & 15;

  // phase 0: stage q = query + query_pos as bf16
  {
    int fidx = tid * 8;
    int row = fidx >> 8, col = fidx & 255;
    long base = ((long)(g0 + row)) * 256 + col;
    float4 a0 = *(const float4*)(query + base);
    float4 a1 = *(const float4*)(query + base + 4);
    float4 p0 = *(const float4*)(query_pos + base);
    float4 p1 = *(const float4*)(query_pos + base + 4);
    float fv[8] = {a0.x + p0.x, a0.y + p0.y, a0.z + p0.z, a0.w + p0.w,
                   a1.x + p1.x, a1.y + p1.y, a1.z + p1.z, a1.w + p1.w};
    *(uint4*)&sQ[row][col] = pack8(fv);
  }
  __syncthreads();

  // phase 1: C[16][768] = q @ wcat (interleaved cols), bf16 result into sC
  f32x4 acc[6] = {};
  for (int s = 0; s < 8; ++s) {
    bf16x8 af = *(const bf16x8*)&sQ[r16][s * 32 + quad * 8];
#pragma unroll
    for (int t6 = 0; t6 < 6; ++t6) {
      int tile = wave * 6 + t6;
      bf16x8 bfg = *(const bf16x8*)(wcat + ((tile * 8 + s) * 64 + lane) * 8);
      acc[t6] = __builtin_amdgcn_mfma_f32_16x16x32_bf16(af, bfg, acc[t6], 0, 0, 0);
    }
  }
  __syncthreads();                       // sQ dead
#pragma unroll
  for (int t6 = 0; t6 < 6; ++t6) {
    int col = (wave * 6 + t6) * 16 + r16;
#pragma unroll
    for (int rr = 0; rr < 4; ++rr)
      sC[quad * 4 + rr][col] = (u16)bf16_of(acc[t6][rr]);
  }
  __syncthreads();

  // phase 2: fused softmax (32-lane shuffle) + record build.
  // thread = (s: 0..255, mh: 0..1); C triple (ax, ay, logit) at sC[m][3s..3s+2].
  // sOff (disjoint region) written directly; sWgt buffered in regs.
  //   sOff = (pix00 + 128) bits 0..13 | dy_flag bit 14    (pix units)
  uint2 wrecs[8];
  {
    const int s = tid & 255, mh = tid >> 8;
    const int l = (s >> 3) & 3;
    const int WlI[4] = {100, 50, 25, 13};
    const int baseI[4] = {0, 10000, 12500, 13125};
    const int Wl = WlI[l], Hl = WlI[l], base = baseI[l];
    const float WlF = (float)Wl;
    const float ba  = b_attn[s];
    const float box = b_off[2 * s], boy = b_off[2 * s + 1];
    const int jsw = (s & 224) | ((s + (s >> 5)) & 31);   // bank swizzle over h
#pragma unroll
    for (int mm = 0; mm < 8; ++mm) {
      int m = mh * 8 + mm;
      const u16* cp = &sC[m][3 * s];
      float ax = b2f(cp[0]), ay = b2f(cp[1]);
      float logit = b2f(cp[2]) + ba;
      float mx = logit;
      mx = fmaxf(mx, __shfl_xor(mx, 1));
      mx = fmaxf(mx, __shfl_xor(mx, 2));
      mx = fmaxf(mx, __shfl_xor(mx, 4));
      mx = fmaxf(mx, __shfl_xor(mx, 8));
      mx = fmaxf(mx, __shfl_xor(mx, 16));
      float e = __expf(logit - mx);
      float sum = e;
      sum += __shfl_xor(sum, 1);
      sum += __shfl_xor(sum, 2);
      sum += __shfl_xor(sum, 4);
      sum += __shfl_xor(sum, 8);
      sum += __shfl_xor(sum, 16);
      float w = e / sum;
      float2 rp = *(const float2*)(refpts + (((long)(g0 + m)) * LL + l) * 2);
      float x = rp.x * WlF + (ax + box) - 0.5f;
      float y = rp.y * WlF + (ay + boy) - 0.5f;
      float fx0 = floorf(x), fy0 = floorf(y);
      int x0 = (int)fx0, y0 = (int)fy0;
      float fx = x - fx0, fy = y - fy0;
      bool xv0 = (x0 >= 0) & (x0 < Wl);
      bool xv1 = (x0 >= -1) & (x0 < Wl - 1);
      bool yv0 = (y0 >= 0) & (y0 < Hl);
      bool yv1 = (y0 >= -1) & (y0 < Hl - 1);
      float w00 = w * (1.f - fx) * (1.f - fy) * (float)(xv0 & yv0);
      float w01 = w * fx * (1.f - fy) * (float)(xv1 & yv0);
      float w10 = w * (1.f - fx) * fy * (float)(xv0 & yv1);
      float w11 = w * fx * fy * (float)(xv1 & yv1);
      int x0a = min(max(x0, -1), Wl - 1);
      int y0a = min(max(y0, -1), Hl - 1);
      int y1c = min(max(y0 + 1, 0), Hl - 1);
      int p00 = base + y0a * Wl + x0a;               // pix units, [-101, 13293]
      int dyf = y1c - y0a;                           // 0 or 1
      wrecs[mm].x = bf16_of(w00) | (bf16_of(w01) << 16);
      wrecs[mm].y = bf16_of(w10) | (bf16_of(w11) << 16);
      sOff[m][jsw] = (u16)((p00 + 128) | (dyf << 14));
    }
  }
  __syncthreads();                       // sC dead
  {
    const int s = tid & 255, mh = tid >> 8;
    const int jsw = (s & 224) | ((s + (s >> 5)) & 31);
#pragma unroll
    for (int mm = 0; mm < 8; ++mm) sWgt[mh * 8 + mm][jsw] = wrecs[mm];
  }
  __syncthreads();

  // phase 3: gather — thread = (m:16, h:8, c4:4); v_ws rows are 512B;
  // x+1 corner = +512B; dy stride = Wl*512 (compile-time per level group).
  {
    const int c4 = tid & 3, hh = (tid >> 2) & 7, m = tid >> 5;
    const u32 vbm = (u32)VWS_OFF + (u32)(b * LENV) * 512u + (u32)hh * 64u
                  + (u32)c4 * 16u - 65536u;          // folds the +128 bias
    float oacc[8] = {};
    const u32 wltab[4] = {51200u, 25600u, 12800u, 6656u};
#pragma unroll
    for (int lv = 0; lv < 4; ++lv) {
      const u32 wl = wltab[lv];
#pragma unroll 4
      for (int ii = 0; ii < 8; ++ii) {
        const int i = lv * 8 + ii;
        const int srow = (hh << 5) | ((i + hh) & 31);
        uint2 wr = sWgt[m][srow];
        u32   po = (u32)sOff[m][srow];
        u32 off0 = vbm + ((po & 0x3FFFu) << 9);
        u32 off1 = off0 + (po >> 14) * wl;
        uint4 q00 = *(const uint4*)(wsb + off0);
        uint4 q01 = *(const uint4*)(wsb + off0 + 512);
        uint4 q10 = *(const uint4*)(wsb + off1);
        uint4 q11 = *(const uint4*)(wsb + off1 + 512);
        acc8(oacc, q00, blo(wr.x));
        acc8(oacc, q01, bhi(wr.x));
        acc8(oacc, q10, blo(wr.y));
        acc8(oacc, q11, bhi(wr.y));
      }
    }
    __syncthreads();                     // tables dead
    *(uint4*)&sO[m][hh * 32 + c4 * 8] = pack8(oacc);
  }
  __syncthreads();

  // phase 4: out = gathered @ W_out + b_out  (16 n-tiles / 8 waves)
  f32x4 acc2[2] = {};
  for (int s = 0; s < 8; ++s) {
    bf16x8 af = *(const bf16x8*)&sO[r16][s * 32 + quad * 8];
#pragma unroll
    for (int t2 = 0; t2 < 2; ++t2) {
      int tile = wave * 2 + t2;
      bf16x8 bfg = *(const bf16x8*)(wout + ((tile * 8 + s) * 64 + lane) * 8);
      acc2[t2] = __builtin_amdgcn_mfma_f32_16x16x32_bf16(af, bfg, acc2[t2], 0, 0, 0);
    }
  }
#pragma unroll
  for (int t2 = 0; t2 < 2; ++t2) {
    int col = (wave * 2 + t2) * 16 + r16;
    float bias = b_out[col];
#pragma unroll
    for (int rr = 0; rr < 4; ++rr) {
      int row = quad * 4 + rr;
      out[((long)(g0 + row)) * 256 + col] = acc2[t2][rr] + bias;
    }
  }
}

extern "C" void kernel_launch(void* const* d_in, const int* in_sizes, int n_in,
                              void* d_out, int out_size, void* d_ws, size_t ws_size,
                              hipStream_t stream) {
  const float* query     = (const float*)d_in[0];
  const float* value     = (const float*)d_in[1];
  const float* query_pos = (const float*)d_in[2];
  const float* refpts    = (const float*)d_in[3];
  const float* W_off     = (const float*)d_in[5];
  const float* b_off     = (const float*)d_in[6];
  const float* W_attn    = (const float*)d_in[7];
  const float* b_attn    = (const float*)d_in[8];
  const float* W_val     = (const float*)d_in[9];
  const float* b_val     = (const float*)d_in[10];
  const float* W_out     = (const float*)d_in[11];
  const float* b_out     = (const float*)d_in[12];
  float* out = (float*)d_out;

  char* ws = (char*)d_ws;
  u16* wcat = (u16*)ws;                                   //    393,216 B @ 0
  u16* v_ws = (u16*)(ws + VWS_OFF);                       // 13,613,056 B
  u16* wval = (u16*)(ws + VWS_OFF + 13613056);            //    131,072 B
  u16* wout = (u16*)(ws + VWS_OFF + 13613056 + 131072);   //    131,072 B

  k_prep<<<dim3(80 * 8), dim3(64), 0, stream>>>(W_off, W_attn, W_val, W_out,
                                                wcat, wval, wout);
  k_valproj<<<dim3((ROWS_V + 63) / 64), dim3(512), 0, stream>>>(value, b_val, wval, v_ws);
  k_attn<<<dim3(BSB * NQq / MQ), dim3(512), 0, stream>>>(
      query, query_pos, refpts, b_off, b_attn, b_out, wcat, wout, ws, out);
}

// Round 11
// 235.561 us; speedup vs baseline: 1.0633x; 1.0022x over previous
//
#include <hip/hip_runtime.h>

// MS Deformable Attention 3D — R13: R12's fused low-LDS k_attn (bf16 sC,
// 40,960B LDS, 4 blocks/CU) + R6's line-efficient v_ws layout [b][h][pix][32]
// (128B lines hold x-adjacent pixels of the SAME head).

#define EE   256
#define HH   8
#define LL   4
#define NQq  10000
#define BSB  2
#define LENV 13294
#define MQ   16
#define ROWS_V (BSB * LENV)   // 26588

// workspace layout (bytes):
//   wcat @ 0          : 393,216    (front guard for v_ws underreads >= -6464B)
//   v_ws @ 393,216    : 13,613,056 ([b][h][pix][32] bf16, 64B rows)
//   wval @ 14,006,272 : 131,072    (back guard for v_ws overreads <= ~6.5KB)
//   wout @ 14,137,344 : 131,072
#define VWS_OFF 393216

typedef unsigned short u16;
typedef unsigned int   u32;
typedef __attribute__((ext_vector_type(8))) short bf16x8;
typedef __attribute__((ext_vector_type(4))) float f32x4;

__device__ __forceinline__ u32 bf16_of(float f) {
  u32 u = __float_as_uint(f);
  return (u + 0x7FFFu + ((u >> 16) & 1u)) >> 16;   // RNE
}
__device__ __forceinline__ float blo(u32 u) { return __uint_as_float(u << 16); }
__device__ __forceinline__ float bhi(u32 u) { return __uint_as_float(u & 0xFFFF0000u); }
__device__ __forceinline__ float b2f(u32 u) { return __uint_as_float(u << 16); }

__device__ __forceinline__ uint4 pack8(const float* f) {
  uint4 u;
  u.x = bf16_of(f[0]) | (bf16_of(f[1]) << 16);
  u.y = bf16_of(f[2]) | (bf16_of(f[3]) << 16);
  u.z = bf16_of(f[4]) | (bf16_of(f[5]) << 16);
  u.w = bf16_of(f[6]) | (bf16_of(f[7]) << 16);
  return u;
}

__device__ __forceinline__ void acc8(float o[8], uint4 q, float w) {
  o[0] += w * blo(q.x); o[1] += w * bhi(q.x);
  o[2] += w * blo(q.y); o[3] += w * bhi(q.y);
  o[4] += w * blo(q.z); o[5] += w * bhi(q.z);
  o[6] += w * blo(q.w); o[7] += w * bhi(q.w);
}

// ---- K0: weights -> bf16 B-fragment layout ----------------------------------
// wcat columns INTERLEAVED: col = 3s+k, k=0/1 -> W_off[:,2s+k], k=2 -> W_attn[:,s]
__global__ __launch_bounds__(64) void k_prep(
    const float* __restrict__ W_off, const float* __restrict__ W_attn,
    const float* __restrict__ W_val, const float* __restrict__ W_out,
    u16* __restrict__ wcat, u16* __restrict__ wval, u16* __restrict__ wout) {
  const int tile = blockIdx.x >> 3, s = blockIdx.x & 7;
  const int l = threadIdx.x, quad = l >> 4, r16 = l & 15;
  float f[8];
  u16* dst;
  if (tile < 48) {            // interleaved concat, 768 cols
    int col = tile * 16 + r16;
    int sc = col / 3, kp = col - sc * 3;
#pragma unroll
    for (int j = 0; j < 8; ++j) {
      int kk = s * 32 + quad * 8 + j;
      f[j] = (kp < 2) ? W_off[kk * 512 + 2 * sc + kp] : W_attn[kk * 256 + sc];
    }
    dst = wcat + ((tile * 8 + s) * 64 + l) * 8;
  } else if (tile < 64) {     // W_val[256x256]
    int col = (tile - 48) * 16 + r16;
#pragma unroll
    for (int j = 0; j < 8; ++j) f[j] = W_val[(s * 32 + quad * 8 + j) * 256 + col];
    dst = wval + (((tile - 48) * 8 + s) * 64 + l) * 8;
  } else {                    // W_out[256x256]
    int col = (tile - 64) * 16 + r16;
#pragma unroll
    for (int j = 0; j < 8; ++j) f[j] = W_out[(s * 32 + quad * 8 + j) * 256 + col];
    dst = wout + (((tile - 64) * 8 + s) * 64 + l) * 8;
  }
  *(uint4*)dst = pack8(f);
}

// ---- K1: value projection -> v_ws [b][h][pix][32] bf16 ----------------------
__global__ __launch_bounds__(512) void k_valproj(
    const float* __restrict__ value, const float* __restrict__ b_val,
    const u16* __restrict__ wval, u16* __restrict__ v_ws) {
  __shared__ __align__(16) u16 sA[64][264];
  const int tid = threadIdx.x;
  const int g0 = blockIdx.x * 64;
#pragma unroll
  for (int ch = 0; ch < 4; ++ch) {
    int fidx = ch * 4096 + tid * 8;
    int row = fidx >> 8, col = fidx & 255;
    int g = g0 + row;
    float fv[8] = {0.f, 0.f, 0.f, 0.f, 0.f, 0.f, 0.f, 0.f};
    if (g < ROWS_V) {
      float4 a = *(const float4*)(value + (long)g * 256 + col);
      float4 b = *(const float4*)(value + (long)g * 256 + col + 4);
      fv[0] = a.x; fv[1] = a.y; fv[2] = a.z; fv[3] = a.w;
      fv[4] = b.x; fv[5] = b.y; fv[6] = b.z; fv[7] = b.w;
    }
    *(uint4*)&sA[row][col] = pack8(fv);
  }
  __syncthreads();
  const int wave = tid >> 6, lane = tid & 63, quad = lane >> 4, r16 = lane & 15;
  f32x4 acc[2][4] = {};
  for (int s = 0; s < 8; ++s) {
    bf16x8 af[4];
#pragma unroll
    for (int mt = 0; mt < 4; ++mt)
      af[mt] = *(const bf16x8*)&sA[mt * 16 + r16][s * 32 + quad * 8];
#pragma unroll
    for (int nt = 0; nt < 2; ++nt) {
      int ntg = wave * 2 + nt;
      bf16x8 bfg = *(const bf16x8*)(wval + ((ntg * 8 + s) * 64 + lane) * 8);
#pragma unroll
      for (int mt = 0; mt < 4; ++mt)
        acc[nt][mt] = __builtin_amdgcn_mfma_f32_16x16x32_bf16(af[mt], bfg, acc[nt][mt], 0, 0, 0);
    }
  }
  __syncthreads();
#pragma unroll
  for (int nt = 0; nt < 2; ++nt) {
    int col = (wave * 2 + nt) * 16 + r16;
    float bias = b_val[col];
#pragma unroll
    for (int mt = 0; mt < 4; ++mt)
#pragma unroll
      for (int rr = 0; rr < 4; ++rr)
        sA[mt * 16 + quad * 4 + rr][col] = (u16)bf16_of(acc[nt][mt][rr] + bias);
  }
  __syncthreads();
  // epilogue: 64 rows x 8 heads x 4 chunks of 16B = 2048 chunks / 512 threads
#pragma unroll
  for (int it = 0; it < 4; ++it) {
    int chunk = it * 512 + tid;        // 0..2047
    int r  = chunk >> 5;               // row 0..63
    int hc = chunk & 31;               // head*4 + quarter
    int h2 = hc >> 2, qq = hc & 3;
    int g = g0 + r;
    if (g < ROWS_V) {
      int bb = g / LENV, pix = g - bb * LENV;
      *(uint4*)(v_ws + ((long)((bb * 8 + h2) * LENV + pix) * 32 + qq * 8)) =
          *(const uint4*)&sA[r][h2 * 32 + qq * 8];
    }
  }
}

// ---- K2: fused; 16 queries/block, 512 threads, 40,960B LDS -> 4 blocks/CU ---
__global__ __launch_bounds__(512, 8) void k_attn(
    const float* __restrict__ query, const float* __restrict__ query_pos,
    const float* __restrict__ refpts,
    const float* __restrict__ b_off, const float* __restrict__ b_attn,
    const float* __restrict__ b_out,
    const u16* __restrict__ wcat, const u16* __restrict__ wout,
    const char* __restrict__ wsb, float* __restrict__ out) {
  __shared__ __align__(16) char smem[40960];
  u16   (*sQ)[264]   = (u16(*)[264])smem;           // staged q (8,448B)
  u16   (*sC)[772]   = (u16(*)[772])smem;           // GEMM1 C bf16 (24,704B, after sQ)
  uint2 (*sWgt)[256] = (uint2(*)[256])smem;         // 32KB (after sC dead)
  u16   (*sOff)[256] = (u16(*)[256])(smem + 32768); // 8KB, disjoint from sC
  u16   (*sO)[264]   = (u16(*)[264])smem;           // gather out (after tables)

  const int tid = threadIdx.x;
  const int g0 = blockIdx.x * MQ;
  const int b = g0 / NQq;
  const int wave = tid >> 6, lane = tid & 63, quad = lane >> 4, r16 = lane & 15;

  // phase 0: stage q = query + query_pos as bf16
  {
    int fidx = tid * 8;
    int row = fidx >> 8, col = fidx & 255;
    long base = ((long)(g0 + row)) * 256 + col;
    float4 a0 = *(const float4*)(query + base);
    float4 a1 = *(const float4*)(query + base + 4);
    float4 p0 = *(const float4*)(query_pos + base);
    float4 p1 = *(const float4*)(query_pos + base + 4);
    float fv[8] = {a0.x + p0.x, a0.y + p0.y, a0.z + p0.z, a0.w + p0.w,
                   a1.x + p1.x, a1.y + p1.y, a1.z + p1.z, a1.w + p1.w};
    *(uint4*)&sQ[row][col] = pack8(fv);
  }
  __syncthreads();

  // phase 1: C[16][768] = q @ wcat (interleaved cols), bf16 result into sC
  f32x4 acc[6] = {};
  for (int s = 0; s < 8; ++s) {
    bf16x8 af = *(const bf16x8*)&sQ[r16][s * 32 + quad * 8];
#pragma unroll
    for (int t6 = 0; t6 < 6; ++t6) {
      int tile = wave * 6 + t6;
      bf16x8 bfg = *(const bf16x8*)(wcat + ((tile * 8 + s) * 64 + lane) * 8);
      acc[t6] = __builtin_amdgcn_mfma_f32_16x16x32_bf16(af, bfg, acc[t6], 0, 0, 0);
    }
  }
  __syncthreads();                       // sQ dead
#pragma unroll
  for (int t6 = 0; t6 < 6; ++t6) {
    int col = (wave * 6 + t6) * 16 + r16;
#pragma unroll
    for (int rr = 0; rr < 4; ++rr)
      sC[quad * 4 + rr][col] = (u16)bf16_of(acc[t6][rr]);
  }
  __syncthreads();

  // phase 2: fused softmax (32-lane shuffle) + record build.
  // thread = (s: 0..255, mh: 0..1); C triple (ax, ay, logit) at sC[m][3s..3s+2].
  //   sOff = (pix00 + 128) bits 0..13 | dy_flag bit 14    (64B-row units)
  uint2 wrecs[8];
  {
    const int s = tid & 255, mh = tid >> 8;
    const int l = (s >> 3) & 3;
    const int WlI[4] = {100, 50, 25, 13};
    const int baseI[4] = {0, 10000, 12500, 13125};
    const int Wl = WlI[l], Hl = WlI[l], base = baseI[l];
    const float WlF = (float)Wl;
    const float ba  = b_attn[s];
    const float box = b_off[2 * s], boy = b_off[2 * s + 1];
    const int jsw = (s & 224) | ((s + (s >> 5)) & 31);   // bank swizzle over h
#pragma unroll
    for (int mm = 0; mm < 8; ++mm) {
      int m = mh * 8 + mm;
      const u16* cp = &sC[m][3 * s];
      float ax = b2f(cp[0]), ay = b2f(cp[1]);
      float logit = b2f(cp[2]) + ba;
      float mx = logit;
      mx = fmaxf(mx, __shfl_xor(mx, 1));
      mx = fmaxf(mx, __shfl_xor(mx, 2));
      mx = fmaxf(mx, __shfl_xor(mx, 4));
      mx = fmaxf(mx, __shfl_xor(mx, 8));
      mx = fmaxf(mx, __shfl_xor(mx, 16));
      float e = __expf(logit - mx);
      float sum = e;
      sum += __shfl_xor(sum, 1);
      sum += __shfl_xor(sum, 2);
      sum += __shfl_xor(sum, 4);
      sum += __shfl_xor(sum, 8);
      sum += __shfl_xor(sum, 16);
      float w = e / sum;
      float2 rp = *(const float2*)(refpts + (((long)(g0 + m)) * LL + l) * 2);
      float x = rp.x * WlF + (ax + box) - 0.5f;
      float y = rp.y * WlF + (ay + boy) - 0.5f;
      float fx0 = floorf(x), fy0 = floorf(y);
      int x0 = (int)fx0, y0 = (int)fy0;
      float fx = x - fx0, fy = y - fy0;
      bool xv0 = (x0 >= 0) & (x0 < Wl);
      bool xv1 = (x0 >= -1) & (x0 < Wl - 1);
      bool yv0 = (y0 >= 0) & (y0 < Hl);
      bool yv1 = (y0 >= -1) & (y0 < Hl - 1);
      float w00 = w * (1.f - fx) * (1.f - fy) * (float)(xv0 & yv0);
      float w01 = w * fx * (1.f - fy) * (float)(xv1 & yv0);
      float w10 = w * (1.f - fx) * fy * (float)(xv0 & yv1);
      float w11 = w * fx * fy * (float)(xv1 & yv1);
      int x0a = min(max(x0, -1), Wl - 1);
      int y0a = min(max(y0, -1), Hl - 1);
      int y1c = min(max(y0 + 1, 0), Hl - 1);
      int p00 = base + y0a * Wl + x0a;               // 64B units, [-101, 13293]
      int dyf = y1c - y0a;                           // 0 or 1
      wrecs[mm].x = bf16_of(w00) | (bf16_of(w01) << 16);
      wrecs[mm].y = bf16_of(w10) | (bf16_of(w11) << 16);
      sOff[m][jsw] = (u16)((p00 + 128) | (dyf << 14));
    }
  }
  __syncthreads();                       // sC dead
  {
    const int s = tid & 255, mh = tid >> 8;
    const int jsw = (s & 224) | ((s + (s >> 5)) & 31);
#pragma unroll
    for (int mm = 0; mm < 8; ++mm) sWgt[mh * 8 + mm][jsw] = wrecs[mm];
  }
  __syncthreads();

  // phase 3: gather — thread = (m:16, h:8, c4:4); 64B rows, x+1 = +64B;
  // dy stride = Wl*64 (compile-time per level group).
  {
    const int c4 = tid & 3, hh = (tid >> 2) & 7, m = tid >> 5;
    const u32 vbm = (u32)VWS_OFF + (u32)(b * 8 + hh) * (u32)(LENV * 64)
                  + (u32)c4 * 16u - 8192u;           // folds the +128 bias
    float oacc[8] = {};
    const u32 wl64tab[4] = {6400u, 3200u, 1600u, 832u};
#pragma unroll
    for (int lv = 0; lv < 4; ++lv) {
      const u32 wl64 = wl64tab[lv];
#pragma unroll 4
      for (int ii = 0; ii < 8; ++ii) {
        const int i = lv * 8 + ii;
        const int srow = (hh << 5) | ((i + hh) & 31);
        uint2 wr = sWgt[m][srow];
        u32   po = (u32)sOff[m][srow];
        u32 off0 = vbm + ((po & 0x3FFFu) << 6);
        u32 off1 = off0 + (po >> 14) * wl64;
        uint4 q00 = *(const uint4*)(wsb + off0);
        uint4 q01 = *(const uint4*)(wsb + off0 + 64);
        uint4 q10 = *(const uint4*)(wsb + off1);
        uint4 q11 = *(const uint4*)(wsb + off1 + 64);
        acc8(oacc, q00, blo(wr.x));
        acc8(oacc, q01, bhi(wr.x));
        acc8(oacc, q10, blo(wr.y));
        acc8(oacc, q11, bhi(wr.y));
      }
    }
    __syncthreads();                     // tables dead
    *(uint4*)&sO[m][hh * 32 + c4 * 8] = pack8(oacc);
  }
  __syncthreads();

  // phase 4: out = gathered @ W_out + b_out  (16 n-tiles / 8 waves)
  f32x4 acc2[2] = {};
  for (int s = 0; s < 8; ++s) {
    bf16x8 af = *(const bf16x8*)&sO[r16][s * 32 + quad * 8];
#pragma unroll
    for (int t2 = 0; t2 < 2; ++t2) {
      int tile = wave * 2 + t2;
      bf16x8 bfg = *(const bf16x8*)(wout + ((tile * 8 + s) * 64 + lane) * 8);
      acc2[t2] = __builtin_amdgcn_mfma_f32_16x16x32_bf16(af, bfg, acc2[t2], 0, 0, 0);
    }
  }
#pragma unroll
  for (int t2 = 0; t2 < 2; ++t2) {
    int col = (wave * 2 + t2) * 16 + r16;
    float bias = b_out[col];
#pragma unroll
    for (int rr = 0; rr < 4; ++rr) {
      int row = quad * 4 + rr;
      out[((long)(g0 + row)) * 256 + col] = acc2[t2][rr] + bias;
    }
  }
}

extern "C" void kernel_launch(void* const* d_in, const int* in_sizes, int n_in,
                              void* d_out, int out_size, void* d_ws, size_t ws_size,
                              hipStream_t stream) {
  const float* query     = (const float*)d_in[0];
  const float* value     = (const float*)d_in[1];
  const float* query_pos = (const float*)d_in[2];
  const float* refpts    = (const float*)d_in[3];
  const float* W_off     = (const float*)d_in[5];
  const float* b_off     = (const float*)d_in[6];
  const float* W_attn    = (const float*)d_in[7];
  const float* b_attn    = (const float*)d_in[8];
  const float* W_val     = (const float*)d_in[9];
  const float* b_val     = (const float*)d_in[10];
  const float* W_out     = (const float*)d_in[11];
  const float* b_out     = (const float*)d_in[12];
  float* out = (float*)d_out;

  char* ws = (char*)d_ws;
  u16* wcat = (u16*)ws;                                   //    393,216 B @ 0
  u16* v_ws = (u16*)(ws + VWS_OFF);                       // 13,613,056 B
  u16* wval = (u16*)(ws + VWS_OFF + 13613056);            //    131,072 B
  u16* wout = (u16*)(ws + VWS_OFF + 13613056 + 131072);   //    131,072 B

  k_prep<<<dim3(80 * 8), dim3(64), 0, stream>>>(W_off, W_attn, W_val, W_out,
                                                wcat, wval, wout);
  k_valproj<<<dim3((ROWS_V + 63) / 64), dim3(512), 0, stream>>>(value, b_val, wval, v_ws);
  k_attn<<<dim3(BSB * NQq / MQ), dim3(512), 0, stream>>>(
      query, query_pos, refpts, b_off, b_attn, b_out, wcat, wout, ws, out);
}

// Round 12
// 229.753 us; speedup vs baseline: 1.0902x; 1.0253x over previous
//
#include <hip/hip_runtime.h>

// MS Deformable Attention 3D — R14 = R10 revert (best measured: 228.0 us,
// k_attn 121). Pair-merged gather (128B spans, shfl_xor(4) x-combine),
// separate softmax phase, 49,408B LDS (3 blocks/CU), 512-thread k_valproj.
// R12/R13's bf16-sC 4-blocks/CU variant regressed (L2 thrash: FETCH +20MB).

#define EE   256
#define HH   8
#define LL   4
#define NQq  10000
#define BSB  2
#define LENV 13294
#define MQ   16
#define ROWS_V (BSB * LENV)   // 26588

// workspace layout (bytes):
//   wcat  @ 0         : 393,216   (front guard for v_ws underreads >= -6464B)
//   v_ws  @ 393,216   : 13,613,056
//   wval  @ 14,006,272: 131,072   (back guard for v_ws overreads <= ~6.5KB)
//   wout  @ 14,137,344: 131,072
#define VWS_OFF 393216

typedef unsigned short u16;
typedef unsigned int   u32;
typedef __attribute__((ext_vector_type(8))) short bf16x8;
typedef __attribute__((ext_vector_type(4))) float f32x4;

__device__ __forceinline__ u32 bf16_of(float f) {
  u32 u = __float_as_uint(f);
  return (u + 0x7FFFu + ((u >> 16) & 1u)) >> 16;   // RNE
}
__device__ __forceinline__ float blo(u32 u) { return __uint_as_float(u << 16); }
__device__ __forceinline__ float bhi(u32 u) { return __uint_as_float(u & 0xFFFF0000u); }

__device__ __forceinline__ uint4 pack8(const float* f) {
  uint4 u;
  u.x = bf16_of(f[0]) | (bf16_of(f[1]) << 16);
  u.y = bf16_of(f[2]) | (bf16_of(f[3]) << 16);
  u.z = bf16_of(f[4]) | (bf16_of(f[5]) << 16);
  u.w = bf16_of(f[6]) | (bf16_of(f[7]) << 16);
  return u;
}

__device__ __forceinline__ void acc8(float o[8], uint4 q, float w) {
  o[0] += w * blo(q.x); o[1] += w * bhi(q.x);
  o[2] += w * blo(q.y); o[3] += w * bhi(q.y);
  o[4] += w * blo(q.z); o[5] += w * bhi(q.z);
  o[6] += w * blo(q.w); o[7] += w * bhi(q.w);
}

// ---- K0: weights -> bf16 B-fragment layout ----------------------------------
__global__ __launch_bounds__(64) void k_prep(
    const float* __restrict__ W_off, const float* __restrict__ W_attn,
    const float* __restrict__ W_val, const float* __restrict__ W_out,
    u16* __restrict__ wcat, u16* __restrict__ wval, u16* __restrict__ wout) {
  const int tile = blockIdx.x >> 3, s = blockIdx.x & 7;
  const int l = threadIdx.x, quad = l >> 4, r16 = l & 15;
  float f[8];
  u16* dst;
  if (tile < 48) {            // concat(W_off[256x512], W_attn[256x256])
    int col = tile * 16 + r16;
#pragma unroll
    for (int j = 0; j < 8; ++j) {
      int k = s * 32 + quad * 8 + j;
      f[j] = (col < 512) ? W_off[k * 512 + col] : W_attn[k * 256 + (col - 512)];
    }
    dst = wcat + ((tile * 8 + s) * 64 + l) * 8;
  } else if (tile < 64) {     // W_val[256x256]
    int col = (tile - 48) * 16 + r16;
#pragma unroll
    for (int j = 0; j < 8; ++j) f[j] = W_val[(s * 32 + quad * 8 + j) * 256 + col];
    dst = wval + (((tile - 48) * 8 + s) * 64 + l) * 8;
  } else {                    // W_out[256x256]
    int col = (tile - 64) * 16 + r16;
#pragma unroll
    for (int j = 0; j < 8; ++j) f[j] = W_out[(s * 32 + quad * 8 + j) * 256 + col];
    dst = wout + (((tile - 64) * 8 + s) * 64 + l) * 8;
  }
  *(uint4*)dst = pack8(f);
}

// ---- K1: value projection, MFMA, 64 rows/block, 512 threads / 8 waves -------
__global__ __launch_bounds__(512) void k_valproj(
    const float* __restrict__ value, const float* __restrict__ b_val,
    const u16* __restrict__ wval, u16* __restrict__ v_ws) {
  __shared__ __align__(16) u16 sA[64][264];
  const int tid = threadIdx.x;
  const int g0 = blockIdx.x * 64;
#pragma unroll
  for (int ch = 0; ch < 4; ++ch) {
    int fidx = ch * 4096 + tid * 8;
    int row = fidx >> 8, col = fidx & 255;
    int g = g0 + row;
    float fv[8] = {0.f, 0.f, 0.f, 0.f, 0.f, 0.f, 0.f, 0.f};
    if (g < ROWS_V) {
      float4 a = *(const float4*)(value + (long)g * 256 + col);
      float4 b = *(const float4*)(value + (long)g * 256 + col + 4);
      fv[0] = a.x; fv[1] = a.y; fv[2] = a.z; fv[3] = a.w;
      fv[4] = b.x; fv[5] = b.y; fv[6] = b.z; fv[7] = b.w;
    }
    *(uint4*)&sA[row][col] = pack8(fv);
  }
  __syncthreads();
  const int wave = tid >> 6, lane = tid & 63, quad = lane >> 4, r16 = lane & 15;
  f32x4 acc[2][4] = {};
  for (int s = 0; s < 8; ++s) {
    bf16x8 af[4];
#pragma unroll
    for (int mt = 0; mt < 4; ++mt)
      af[mt] = *(const bf16x8*)&sA[mt * 16 + r16][s * 32 + quad * 8];
#pragma unroll
    for (int nt = 0; nt < 2; ++nt) {
      int ntg = wave * 2 + nt;
      bf16x8 bfg = *(const bf16x8*)(wval + ((ntg * 8 + s) * 64 + lane) * 8);
#pragma unroll
      for (int mt = 0; mt < 4; ++mt)
        acc[nt][mt] = __builtin_amdgcn_mfma_f32_16x16x32_bf16(af[mt], bfg, acc[nt][mt], 0, 0, 0);
    }
  }
  __syncthreads();
#pragma unroll
  for (int nt = 0; nt < 2; ++nt) {
    int col = (wave * 2 + nt) * 16 + r16;
    float bias = b_val[col];
#pragma unroll
    for (int mt = 0; mt < 4; ++mt)
#pragma unroll
      for (int rr = 0; rr < 4; ++rr)
        sA[mt * 16 + quad * 4 + rr][col] = (u16)bf16_of(acc[nt][mt][rr] + bias);
  }
  __syncthreads();
#pragma unroll
  for (int it = 0; it < 4; ++it) {
    int chunk = it * 512 + tid;        // 0..2047
    int r  = chunk >> 5;               // row 0..63
    int hc = chunk & 31;               // head*4 + quarter
    int h2 = hc >> 2, qq = hc & 3;
    int g = g0 + r;
    if (g < ROWS_V) {
      int bb = g / LENV, pix = g - bb * LENV;
      *(uint4*)(v_ws + ((long)((bb * 8 + h2) * LENV + pix) * 32 + qq * 8)) =
          *(const uint4*)&sA[r][h2 * 32 + qq * 8];
    }
  }
}

// ---- K2: 16 queries/block, 512 threads ---------------------------------------
__global__ __launch_bounds__(512, 6) void k_attn(
    const float* __restrict__ query, const float* __restrict__ query_pos,
    const float* __restrict__ refpts,
    const float* __restrict__ b_off, const float* __restrict__ b_attn,
    const float* __restrict__ b_out,
    const u16* __restrict__ wcat, const u16* __restrict__ wout,
    const char* __restrict__ wsb, float* __restrict__ out) {
  __shared__ __align__(16) char smem[49408];
  u16   (*sQ)[264]   = (u16(*)[264])smem;          // staged q (bf16)
  float (*sC)[772]   = (float(*)[772])smem;        // GEMM1 C (after sQ dead)
  uint2 (*sWgt)[256] = (uint2(*)[256])smem;        // record weights (after sC dead)
  u32   (*sOff)[256] = (u32(*)[256])(smem + 32768);// packed o00|dy
  u16   (*sO)[264]   = (u16(*)[264])smem;          // gather output (after tables dead)

  const int tid = threadIdx.x;
  const int g0 = blockIdx.x * MQ;
  const int b = g0 / NQq;
  const int q0 = g0 - b * NQq;
  const int wave = tid >> 6, lane = tid & 63, quad = lane >> 4, r16 = lane & 15;

  // phase 0: stage q = query + query_pos as bf16
  {
    int fidx = tid * 8;
    int row = fidx >> 8, col = fidx & 255;
    long base = ((long)(b * NQq + q0 + row)) * 256 + col;
    float4 a0 = *(const float4*)(query + base);
    float4 a1 = *(const float4*)(query + base + 4);
    float4 p0 = *(const float4*)(query_pos + base);
    float4 p1 = *(const float4*)(query_pos + base + 4);
    float fv[8] = {a0.x + p0.x, a0.y + p0.y, a0.z + p0.z, a0.w + p0.w,
                   a1.x + p1.x, a1.y + p1.y, a1.z + p1.z, a1.w + p1.w};
    *(uint4*)&sQ[row][col] = pack8(fv);
  }
  __syncthreads();

  // phase 1: C[16][768] = q @ concat(W_off, W_attn)   (48 n-tiles / 8 waves)
  f32x4 acc[6] = {};
  for (int s = 0; s < 8; ++s) {
    bf16x8 af = *(const bf16x8*)&sQ[r16][s * 32 + quad * 8];
#pragma unroll
    for (int t6 = 0; t6 < 6; ++t6) {
      int tile = wave * 6 + t6;
      bf16x8 bfg = *(const bf16x8*)(wcat + ((tile * 8 + s) * 64 + lane) * 8);
      acc[t6] = __builtin_amdgcn_mfma_f32_16x16x32_bf16(af, bfg, acc[t6], 0, 0, 0);
    }
  }
  __syncthreads();                       // sQ dead
#pragma unroll
  for (int t6 = 0; t6 < 6; ++t6) {
    int col = (wave * 6 + t6) * 16 + r16;
#pragma unroll
    for (int rr = 0; rr < 4; ++rr)
      sC[quad * 4 + rr][col] = acc[t6][rr];
  }
  __syncthreads();

  // phase 2: softmax per (m, h) over 32 logits; thread = (m, h, g), g owns 8
  {
    const int m = tid >> 5, hh = (tid >> 2) & 7, g = tid & 3;
    float* p = &sC[m][512 + hh * 32 + g * 8];
    const float* ba = b_attn + hh * 32 + g * 8;
    float v[8];
    float mx = -1e30f;
#pragma unroll
    for (int j = 0; j < 8; ++j) { v[j] = p[j] + ba[j]; mx = fmaxf(mx, v[j]); }
    mx = fmaxf(mx, __shfl_xor(mx, 1));
    mx = fmaxf(mx, __shfl_xor(mx, 2));
    float sum = 0.f;
#pragma unroll
    for (int j = 0; j < 8; ++j) { v[j] = __expf(v[j] - mx); sum += v[j]; }
    sum += __shfl_xor(sum, 1);
    sum += __shfl_xor(sum, 2);
    float inv = 1.f / sum;
#pragma unroll
    for (int j = 0; j < 8; ++j) p[j] = v[j] * inv;
  }
  __syncthreads();

  // phase 3: build packed records.
  //   wgt = (w00|w01, w10|w11) bf16 pairs
  //   off = (o00/64 + 128) bits 0..13  |  (dy/64) << 14   (dy/64 <= 100)
  // o00 byte offset of corner00, x/y clamped to [-1, Wl-1]; x+1 corner = +64B.
  // Invalid corners have weight 0; guard reads land in wcat/wval around v_ws.
  // Table column swizzle: col(s,m) = (s & 224) | ((s + m) & 31) — spreads the
  // gather's per-m broadcast reads (wave-uniform s) across 16 distinct banks.
  uint2 wrecs[8];
  u32   orecs[8];
  {
    const int s = tid & 255, mh = tid >> 8;
    const int l = (s >> 3) & 3;
    const int WlI[4] = {100, 50, 25, 13};
    const int baseI[4] = {0, 10000, 12500, 13125};
    const int Wl = WlI[l], Hl = WlI[l], base = baseI[l];
    const float WlF = (float)Wl;
    const float box = b_off[2 * s], boy = b_off[2 * s + 1];
#pragma unroll
    for (int mm = 0; mm < 8; ++mm) {
      int m = mh * 8 + mm;
      float w = sC[m][512 + s];
      float ax = sC[m][2 * s], ay = sC[m][2 * s + 1];
      float2 rp = *(const float2*)(refpts + (((long)(b * NQq + q0 + m)) * LL + l) * 2);
      float x = rp.x * WlF + (ax + box) - 0.5f;
      float y = rp.y * WlF + (ay + boy) - 0.5f;
      float fx0 = floorf(x), fy0 = floorf(y);
      int x0 = (int)fx0, y0 = (int)fy0;
      float fx = x - fx0, fy = y - fy0;
      bool xv0 = (x0 >= 0) & (x0 < Wl);
      bool xv1 = (x0 >= -1) & (x0 < Wl - 1);
      bool yv0 = (y0 >= 0) & (y0 < Hl);
      bool yv1 = (y0 >= -1) & (y0 < Hl - 1);
      float w00 = w * (1.f - fx) * (1.f - fy) * (float)(xv0 & yv0);
      float w01 = w * fx * (1.f - fy) * (float)(xv1 & yv0);
      float w10 = w * (1.f - fx) * fy * (float)(xv0 & yv1);
      float w11 = w * fx * fy * (float)(xv1 & yv1);
      int x0a = min(max(x0, -1), Wl - 1);
      int y0a = min(max(y0, -1), Hl - 1);
      int y1c = min(max(y0 + 1, 0), Hl - 1);
      int o00u = base + y0a * Wl + x0a;              // 64B units, [-101, 13293]
      u32 dyu  = (u32)((y1c - y0a) * Wl);            // 64B units, 0..100
      wrecs[mm].x = bf16_of(w00) | (bf16_of(w01) << 16);
      wrecs[mm].y = bf16_of(w10) | (bf16_of(w11) << 16);
      orecs[mm]   = (u32)(o00u + 128) | (dyu << 14);
    }
  }
  __syncthreads();                       // sC dead
  {
    const int s = tid & 255, mh = tid >> 8;
#pragma unroll
    for (int mm = 0; mm < 8; ++mm) {
      int m = mh * 8 + mm;
      int col = (s & 224) | ((s + m) & 31);
      sWgt[m][col] = wrecs[mm];
      sOff[m][col] = orecs[mm];
    }
  }
  __syncthreads();

  // phase 4: pair-merged gather. 8 lanes per (m,h) group; each group handles
  // m0 and m0+8. Lanes 0-3 read the x0 row, lanes 4-7 the x1 row (+64B) —
  // each y-pair is ONE contiguous 128B span. x-combine via shfl_xor(4).
  {
    const int c8 = tid & 7, g8 = tid >> 3;
    const int m0 = g8 & 7, hh = g8 >> 3;
    const int xsel = c8 >> 2;            // 0: x0 corner, 1: x1 corner
    const int sb = hh << 5;
    const u32 vbm = (u32)VWS_OFF + (u32)(b * 8 + hh) * (u32)(LENV * 64)
                  + (u32)(c8 & 3) * 16u + (u32)xsel * 64u - 8192u;
    float oa[8] = {}, ob[8] = {};
#pragma unroll 4
    for (int i = 0; i < 32; ++i) {
      const int colA = sb | ((i + m0) & 31);
      const int colB = sb | ((i + m0 + 8) & 31);
      uint2 wrA = sWgt[m0][colA];
      u32   poA = sOff[m0][colA];
      uint2 wrB = sWgt[m0 + 8][colB];
      u32   poB = sOff[m0 + 8][colB];
      u32 a0 = vbm + ((poA & 0x3FFFu) << 6);
      u32 a1 = a0 + ((poA >> 14) << 6);
      u32 b0 = vbm + ((poB & 0x3FFFu) << 6);
      u32 b1 = b0 + ((poB >> 14) << 6);
      uint4 qa0 = *(const uint4*)(wsb + a0);
      uint4 qa1 = *(const uint4*)(wsb + a1);
      uint4 qb0 = *(const uint4*)(wsb + b0);
      uint4 qb1 = *(const uint4*)(wsb + b1);
      float wA0 = xsel ? bhi(wrA.x) : blo(wrA.x);  // w01 : w00
      float wA1 = xsel ? bhi(wrA.y) : blo(wrA.y);  // w11 : w10
      float wB0 = xsel ? bhi(wrB.x) : blo(wrB.x);
      float wB1 = xsel ? bhi(wrB.y) : blo(wrB.y);
      acc8(oa, qa0, wA0);
      acc8(oa, qa1, wA1);
      acc8(ob, qb0, wB0);
      acc8(ob, qb1, wB1);
    }
#pragma unroll
    for (int j = 0; j < 8; ++j) {
      oa[j] += __shfl_xor(oa[j], 4);
      ob[j] += __shfl_xor(ob[j], 4);
    }
    __syncthreads();                     // tables dead
    if (!xsel) {
      *(uint4*)&sO[m0][hh * 32 + c8 * 8]     = pack8(oa);
      *(uint4*)&sO[m0 + 8][hh * 32 + c8 * 8] = pack8(ob);
    }
  }
  __syncthreads();

  // phase 5: out = gathered @ W_out + b_out  (16 n-tiles / 8 waves)
  f32x4 acc2[2] = {};
  for (int s = 0; s < 8; ++s) {
    bf16x8 af = *(const bf16x8*)&sO[r16][s * 32 + quad * 8];
#pragma unroll
    for (int t2 = 0; t2 < 2; ++t2) {
      int tile = wave * 2 + t2;
      bf16x8 bfg = *(const bf16x8*)(wout + ((tile * 8 + s) * 64 + lane) * 8);
      acc2[t2] = __builtin_amdgcn_mfma_f32_16x16x32_bf16(af, bfg, acc2[t2], 0, 0, 0);
    }
  }
#pragma unroll
  for (int t2 = 0; t2 < 2; ++t2) {
    int col = (wave * 2 + t2) * 16 + r16;
    float bias = b_out[col];
#pragma unroll
    for (int rr = 0; rr < 4; ++rr) {
      int row = quad * 4 + rr;
      out[((long)(b * NQq + q0 + row)) * 256 + col] = acc2[t2][rr] + bias;
    }
  }
}

extern "C" void kernel_launch(void* const* d_in, const int* in_sizes, int n_in,
                              void* d_out, int out_size, void* d_ws, size_t ws_size,
                              hipStream_t stream) {
  const float* query     = (const float*)d_in[0];
  const float* value     = (const float*)d_in[1];
  const float* query_pos = (const float*)d_in[2];
  const float* refpts    = (const float*)d_in[3];
  const float* W_off     = (const float*)d_in[5];
  const float* b_off     = (const float*)d_in[6];
  const float* W_attn    = (const float*)d_in[7];
  const float* b_attn    = (const float*)d_in[8];
  const float* W_val     = (const float*)d_in[9];
  const float* b_val     = (const float*)d_in[10];
  const float* W_out     = (const float*)d_in[11];
  const float* b_out     = (const float*)d_in[12];
  float* out = (float*)d_out;

  char* ws = (char*)d_ws;
  u16* wcat = (u16*)ws;                                   //    393,216 B @ 0
  u16* v_ws = (u16*)(ws + VWS_OFF);                       // 13,613,056 B
  u16* wval = (u16*)(ws + VWS_OFF + 13613056);            //    131,072 B
  u16* wout = (u16*)(ws + VWS_OFF + 13613056 + 131072);   //    131,072 B

  k_prep<<<dim3(80 * 8), dim3(64), 0, stream>>>(W_off, W_attn, W_val, W_out,
                                                wcat, wval, wout);
  k_valproj<<<dim3((ROWS_V + 63) / 64), dim3(512), 0, stream>>>(value, b_val, wval, v_ws);
  k_attn<<<dim3(BSB * NQq / MQ), dim3(512), 0, stream>>>(
      query, query_pos, refpts, b_off, b_attn, b_out, wcat, wout, ws, out);
}